// Round 3
// baseline (3322.667 us; speedup 1.0000x reference)
//
#include <hip/hip_runtime.h>
#include <hip/hip_bf16.h>
#include <math.h>

// Sizes
#define S 12
#define C 32
#define T 7
#define L2T 24            // 2*S tokens
#define H 16
#define D 32
#define DH 512            // H*D
#define GIN 12240         // S*S*(T*S+1)
#define GOUT 4608         // S*S*C
#define EPS 1e-5f

__device__ __forceinline__ float dot4(float4 a, float4 b) {
    return a.x * b.x + a.y * b.y + a.z * b.z + a.w * b.w;
}

// ---------------- prep: build gi[3][12240] ----------------
__global__ __launch_bounds__(256) void k_prep(
    const float* __restrict__ it, const float* __restrict__ is_,
    const float* __restrict__ s2w, const float* __restrict__ s2b,
    float* __restrict__ gi)
{
    int idx = blockIdx.x * 256 + threadIdx.x;
    if (idx >= 3 * GIN) return;
    int i = idx / GIN, rem = idx % GIN;
    int ab = rem / 85, e = rem % 85;
    int a = ab / S, b = ab % S;
    float val;
    if (e < 84) {
        int k = e / T, t = e % T;
        int x, y, z;
        if (i == 0)      { x = a; y = b; z = k; }
        else if (i == 1) { x = b; y = k; z = a; }
        else             { x = k; y = a; z = b; }
        val = it[((t * S + x) * S + y) * S + z];
    } else {
        float acc = s2b[i * 144 + ab];
        const float* wr = s2w + (i * 144 + ab) * 8;
        #pragma unroll
        for (int u = 0; u < 8; u++) acc += wr[u] * is_[u];
        val = acc;
    }
    gi[idx] = val;
}

// ---------------- g2g: x[i] = W[i] @ gi[i] + b[i], one wave per row ----------------
__global__ __launch_bounds__(256) void k_g2g(
    const float* __restrict__ W, const float* __restrict__ gb,
    const float* __restrict__ gi, float* __restrict__ xbuf)
{
    int wave = threadIdx.x >> 6;
    int lane = threadIdx.x & 63;
    int r = blockIdx.x * 4 + wave;          // 0..13823
    int i = r / GOUT, rr = r % GOUT;
    const float4* Wr = reinterpret_cast<const float4*>(W + (size_t)r * GIN);
    const float4* gv = reinterpret_cast<const float4*>(gi + i * GIN);
    float acc = 0.f;
    for (int k = lane; k < GIN / 4; k += 64) {
        float4 w4 = Wr[k];
        float4 g4 = gv[k];
        acc += w4.x * g4.x + w4.y * g4.y + w4.z * g4.z + w4.w * g4.w;
    }
    #pragma unroll
    for (int off = 32; off; off >>= 1) acc += __shfl_down(acc, off, 64);
    if (lane == 0) xbuf[i * (2 * GOUT) + rr] = acc + gb[r];   // parity 0
}

// ---------------- fused stage: LN + 16-head attention + residual + LN + FFN ----------------
// One block per slice s (12 blocks, 512 threads). Block s writes row s of BOTH
// out_m1 and out_m2 (the reference transposes x[m2] on writeback:
// x[m2] = c[:, S:, :], i.e. the token read from x[m2][r,s] lands at x[m2][s,r]).
__global__ __launch_bounds__(512) void k_stage(
    const float* __restrict__ xm1, const float* __restrict__ xm2,
    const float* __restrict__ lnxg, const float* __restrict__ lnxb,
    const float* __restrict__ lnyg, const float* __restrict__ lnyb,
    const float* __restrict__ wqw, const float* __restrict__ wqb,
    const float* __restrict__ wkw, const float* __restrict__ wkb,
    const float* __restrict__ wvw, const float* __restrict__ wvb,
    const float* __restrict__ l1w, const float* __restrict__ l1b,
    const float* __restrict__ lnfg, const float* __restrict__ lnfb,
    const float* __restrict__ l2w, const float* __restrict__ l2b,
    const float* __restrict__ l3w, const float* __restrict__ l3b,
    float* __restrict__ out_m1, float* __restrict__ out_m2, int l)
{
    __shared__ float smem[11156];   // 44.6 KB
    float* a    = smem;             // 768, kept for residual
    float* xn   = smem + 768;       // 768
    float* yn   = smem + 1536;      // 768
    float* qs   = smem + 2304;      // [2][768]
    float* ks   = smem + 3840;      // [2][768]
    float* vs   = smem + 5376;      // [2][768]
    float* os   = smem + 6912;      // [2][768]
    float* scs  = smem + 8448;      // [2][576]
    float* xacc = smem + 9600;      // [2][768]
    float* red  = smem + 11136;     // 20
    // FFN-phase aliases (regions free after head loop):
    float* x  = smem + 768;         // = xn
    float* hn = smem + 1536;        // = yn
    float* g  = smem + 2304;        // 3072 floats = q+k region

    int s = blockIdx.x;
    int tid = threadIdx.x;
    int sub = tid >> 8;             // head-group 0/1
    int t   = tid & 255;
    int ls = l * S + s;

    // ---- load a = [x[m1][s] ; x[m2][:,s]] and zero xacc ----
    for (int idx = tid; idx < 768; idx += 512) {
        int r = idx >> 5, c = idx & 31;
        a[idx] = (r < S) ? xm1[s * 384 + r * 32 + c]
                         : xm2[(r - S) * 384 + s * 32 + c];
        xacc[idx] = 0.f; xacc[768 + idx] = 0.f;
    }
    __syncthreads();

    // ---- full-matrix LN stats (shared by xn and yn) ----
    {
        float s1 = 0.f, s2 = 0.f;
        for (int idx = tid; idx < 768; idx += 512) { float z = a[idx]; s1 += z; s2 += z * z; }
        #pragma unroll
        for (int off = 32; off; off >>= 1) { s1 += __shfl_down(s1, off, 64); s2 += __shfl_down(s2, off, 64); }
        if ((tid & 63) == 0) { red[(tid >> 6) * 2] = s1; red[(tid >> 6) * 2 + 1] = s2; }
        __syncthreads();
        if (tid == 0) {
            float t1 = 0.f, t2 = 0.f;
            #pragma unroll
            for (int w = 0; w < 8; w++) { t1 += red[w * 2]; t2 += red[w * 2 + 1]; }
            float mu = t1 * (1.f / 768.f);
            float var = t2 * (1.f / 768.f) - mu * mu;
            red[16] = mu;
            red[17] = rsqrtf(var + EPS);
        }
        __syncthreads();
    }
    float mu = red[16], rs = red[17];

    const float* gx = lnxg + ls * 768; const float* bx = lnxb + ls * 768;
    const float* gy = lnyg + ls * 768; const float* by = lnyb + ls * 768;
    for (int idx = tid; idx < 768; idx += 512) {
        float zn = (a[idx] - mu) * rs;
        xn[idx] = zn * gx[idx] + bx[idx];
        yn[idx] = zn * gy[idx] + by[idx];
    }
    __syncthreads();

    // ---- head loop: 2 heads per iteration (one per 256-thread group) ----
    float* q  = qs  + sub * 768;
    float* kk = ks  + sub * 768;
    float* vv = vs  + sub * 768;
    float* oo = os  + sub * 768;
    float* sc = scs + sub * 576;
    float* xa = xacc + sub * 768;

    for (int hg = 0; hg < 8; hg++) {
        int h = hg * 2 + sub;
        const float4* wq4 = (const float4*)(wqw + (size_t)ls * 16384 + h * 1024);
        const float4* wk4 = (const float4*)(wkw + (size_t)ls * 16384 + h * 1024);
        const float4* wv4 = (const float4*)(wvw + (size_t)ls * 16384 + h * 1024);
        const float* qb = wqb + ls * 512 + h * 32;
        const float* kb = wkb + ls * 512 + h * 32;
        const float* vb = wvb + ls * 512 + h * 32;

        // qkv: 768 elems per head
        for (int idx = t; idx < 768; idx += 256) {
            int r = idx >> 5, j = idx & 31;
            const float4* xr = (const float4*)(xn + r * 32);
            const float4* yr = (const float4*)(yn + r * 32);
            float aq = qb[j], ak = kb[j], av = vb[j];
            #pragma unroll
            for (int c4 = 0; c4 < 8; c4++) {
                float4 xv = xr[c4], yv = yr[c4];
                aq += dot4(xv, wq4[j * 8 + c4]);
                ak += dot4(yv, wk4[j * 8 + c4]);
                av += dot4(yv, wv4[j * 8 + c4]);
            }
            q[idx] = aq; kk[idx] = ak; vv[idx] = av;
        }
        __syncthreads();

        // scores 24x24 (no softmax)
        for (int idx = t; idx < 576; idx += 256) {
            int r = idx / 24, j = idx - r * 24;
            const float4* qr = (const float4*)(q + r * 32);
            const float4* kr = (const float4*)(kk + j * 32);
            float acc = 0.f;
            #pragma unroll
            for (int c4 = 0; c4 < 8; c4++) acc += dot4(qr[c4], kr[c4]);
            sc[idx] = acc * 0.17677669529663687f;   // 1/sqrt(32)
        }
        __syncthreads();

        // o = sc @ v (24x32)
        for (int idx = t; idx < 768; idx += 256) {
            int r = idx >> 5, c = idx & 31;
            const float* sr = sc + r * 24;
            float acc = 0.f;
            #pragma unroll
            for (int j = 0; j < 24; j++) acc += sr[j] * vv[j * 32 + c];
            oo[idx] = acc;
        }
        __syncthreads();

        // xacc += o_h @ w1_h^T
        const float4* w14 = (const float4*)(l1w + (size_t)ls * 16384 + h * 32);
        for (int idx = t; idx < 768; idx += 256) {
            int r = idx >> 5, j = idx & 31;
            const float4* orow = (const float4*)(oo + r * 32);
            float acc = 0.f;
            #pragma unroll
            for (int c4 = 0; c4 < 8; c4++) acc += dot4(orow[c4], w14[j * 128 + c4]);
            xa[idx] += acc;
        }
        __syncthreads();
    }

    // ---- x = a + b1 + sum(head partials) ----
    const float* b1 = l1b + ls * 32;
    for (int idx = tid; idx < 768; idx += 512)
        x[idx] = a[idx] + b1[idx & 31] + xacc[idx] + xacc[768 + idx];
    __syncthreads();

    // ---- LN over x ----
    {
        float s1 = 0.f, s2 = 0.f;
        for (int idx = tid; idx < 768; idx += 512) { float z = x[idx]; s1 += z; s2 += z * z; }
        #pragma unroll
        for (int off = 32; off; off >>= 1) { s1 += __shfl_down(s1, off, 64); s2 += __shfl_down(s2, off, 64); }
        if ((tid & 63) == 0) { red[(tid >> 6) * 2] = s1; red[(tid >> 6) * 2 + 1] = s2; }
        __syncthreads();
        if (tid == 0) {
            float t1 = 0.f, t2 = 0.f;
            #pragma unroll
            for (int w = 0; w < 8; w++) { t1 += red[w * 2]; t2 += red[w * 2 + 1]; }
            float mu2 = t1 * (1.f / 768.f);
            float var = t2 * (1.f / 768.f) - mu2 * mu2;
            red[18] = mu2;
            red[19] = rsqrtf(var + EPS);
        }
        __syncthreads();
    }
    float mu2 = red[18], rs2 = red[19];
    const float* gf = lnfg + ls * 768; const float* bf = lnfb + ls * 768;
    for (int idx = tid; idx < 768; idx += 512)
        hn[idx] = (x[idx] - mu2) * rs2 * gf[idx] + bf[idx];
    __syncthreads();

    // ---- g = gelu(hn @ w2^T + b2)  (24x128), exact gelu ----
    const float4* w24 = (const float4*)(l2w + (size_t)ls * 4096);
    const float* b2 = l2b + ls * 128;
    for (int idx = tid; idx < 3072; idx += 512) {
        int r = idx >> 7, u = idx & 127;
        const float4* hr = (const float4*)(hn + r * 32);
        float acc = b2[u];
        #pragma unroll
        for (int c4 = 0; c4 < 8; c4++) acc += dot4(hr[c4], w24[u * 8 + c4]);
        g[idx] = acc * 0.5f * (1.f + erff(acc * 0.70710678118654752f));
    }
    __syncthreads();

    // ---- out = x + g @ w3^T + b3 ----
    // c[:, :S, :] -> x[m1][s][r] ; c[:, S:, :] -> x[m2][s][r-S]  (row s of both!)
    const float4* w34 = (const float4*)(l3w + (size_t)ls * 4096);
    const float* b3 = l3b + ls * 32;
    for (int idx = tid; idx < 768; idx += 512) {
        int r = idx >> 5, j = idx & 31;
        const float4* gr = (const float4*)(g + r * 128);
        float acc = x[idx] + b3[j];
        #pragma unroll
        for (int u4 = 0; u4 < 32; u4++) acc += dot4(gr[u4], w34[j * 32 + u4]);
        if (r < S) out_m1[s * 384 + r * 32 + j] = acc;
        else       out_m2[s * 384 + (r - S) * 32 + j] = acc;
    }
}

// ---------------- pack: out[(a*3+i)*12+b][c] = x_i[a][b][c] ----------------
__global__ __launch_bounds__(256) void k_pack(
    const float* __restrict__ x0, const float* __restrict__ x1,
    const float* __restrict__ x2, float* __restrict__ out)
{
    int idx = blockIdx.x * 256 + threadIdx.x;
    if (idx >= 3 * 144 * 32) return;
    int c = idx & 31;
    int r = idx >> 5;
    int b = r % 12;
    int ai = r / 12;
    int i = ai % 3;
    int a = ai / 3;
    const float* xs = (i == 0) ? x0 : ((i == 1) ? x1 : x2);
    out[idx] = xs[a * 384 + b * 32 + c];
}

extern "C" void kernel_launch(void* const* d_in, const int* in_sizes, int n_in,
                              void* d_out, int out_size, void* d_ws, size_t ws_size,
                              hipStream_t stream) {
    const float* input_t = (const float*)d_in[0];
    const float* input_s = (const float*)d_in[1];
    const float* s2g_w   = (const float*)d_in[2];
    const float* s2g_b   = (const float*)d_in[3];
    const float* g2g_w   = (const float*)d_in[4];
    const float* g2g_b   = (const float*)d_in[5];
    const float* lnx_g   = (const float*)d_in[6];
    const float* lnx_b   = (const float*)d_in[7];
    const float* lny_g   = (const float*)d_in[8];
    const float* lny_b   = (const float*)d_in[9];
    const float* lnf_g   = (const float*)d_in[10];
    const float* lnf_b   = (const float*)d_in[11];
    const float* wq_w    = (const float*)d_in[12];
    const float* wq_b    = (const float*)d_in[13];
    const float* wk_w    = (const float*)d_in[14];
    const float* wk_b    = (const float*)d_in[15];
    const float* wv_w    = (const float*)d_in[16];
    const float* wv_b    = (const float*)d_in[17];
    const float* l1_w    = (const float*)d_in[18];
    const float* l1_b    = (const float*)d_in[19];
    const float* l2_w    = (const float*)d_in[20];
    const float* l2_b    = (const float*)d_in[21];
    const float* l3_w    = (const float*)d_in[22];
    const float* l3_b    = (const float*)d_in[23];

    float* ws = (float*)d_ws;
    float* gi   = ws;                 // 3*12240 = 36720
    float* xbuf = ws + 36720;         // 3*2*4608 = 27648

    k_prep<<<144, 256, 0, stream>>>(input_t, input_s, s2g_w, s2g_b, gi);
    k_g2g<<<3456, 256, 0, stream>>>(g2g_w, g2g_b, gi, xbuf);

    int par[3] = {0, 0, 0};
    const int pairs[3][2] = {{0, 1}, {2, 0}, {1, 2}};
    for (int l = 0; l < 8; l++) {
        for (int pp = 0; pp < 3; pp++) {
            int m1 = pairs[pp][0], m2 = pairs[pp][1];
            float* in1  = xbuf + m1 * 9216 + par[m1] * 4608;
            float* in2  = xbuf + m2 * 9216 + par[m2] * 4608;
            float* out1 = xbuf + m1 * 9216 + (1 - par[m1]) * 4608;
            float* out2 = xbuf + m2 * 9216 + (1 - par[m2]) * 4608;
            k_stage<<<12, 512, 0, stream>>>(in1, in2,
                lnx_g, lnx_b, lny_g, lny_b,
                wq_w, wq_b, wk_w, wk_b, wv_w, wv_b,
                l1_w, l1_b, lnf_g, lnf_b,
                l2_w, l2_b, l3_w, l3_b,
                out1, out2, l);
            par[m1] ^= 1; par[m2] ^= 1;
        }
    }
    k_pack<<<54, 256, 0, stream>>>(
        xbuf + 0 * 9216 + par[0] * 4608,
        xbuf + 1 * 9216 + par[1] * 4608,
        xbuf + 2 * 9216 + par[2] * 4608,
        (float*)d_out);
}

// Round 4
// 2152.750 us; speedup vs baseline: 1.5435x; 1.5435x over previous
//
#include <hip/hip_runtime.h>
#include <hip/hip_bf16.h>
#include <hip/hip_cooperative_groups.h>
#include <math.h>

namespace cg = cooperative_groups;

// Sizes
#define S 12
#define C 32
#define T 7
#define GIN 12240         // S*S*(T*S+1)
#define GOUT 4608         // S*S*C
#define EPS 1e-5f

__device__ __forceinline__ float dot4(float4 a, float4 b) {
    return a.x * b.x + a.y * b.y + a.z * b.z + a.w * b.w;
}

// ---------------- prep: build gi[3][12240] ----------------
__global__ __launch_bounds__(256) void k_prep(
    const float* __restrict__ it, const float* __restrict__ is_,
    const float* __restrict__ s2w, const float* __restrict__ s2b,
    float* __restrict__ gi)
{
    int idx = blockIdx.x * 256 + threadIdx.x;
    if (idx >= 3 * GIN) return;
    int i = idx / GIN, rem = idx % GIN;
    int ab = rem / 85, e = rem % 85;
    int a = ab / S, b = ab % S;
    float val;
    if (e < 84) {
        int k = e / T, t = e % T;
        int x, y, z;
        if (i == 0)      { x = a; y = b; z = k; }
        else if (i == 1) { x = b; y = k; z = a; }
        else             { x = k; y = a; z = b; }
        val = it[((t * S + x) * S + y) * S + z];
    } else {
        float acc = s2b[i * 144 + ab];
        const float* wr = s2w + (i * 144 + ab) * 8;
        #pragma unroll
        for (int u = 0; u < 8; u++) acc += wr[u] * is_[u];
        val = acc;
    }
    gi[idx] = val;
}

// ---------------- g2g: x[i] = W[i] @ gi[i] + b[i], one wave per row ----------------
__global__ __launch_bounds__(256) void k_g2g(
    const float* __restrict__ W, const float* __restrict__ gb,
    const float* __restrict__ gi, float* __restrict__ xbuf)
{
    int wave = threadIdx.x >> 6;
    int lane = threadIdx.x & 63;
    int r = blockIdx.x * 4 + wave;          // 0..13823
    int i = r / GOUT, rr = r % GOUT;
    const float4* Wr = reinterpret_cast<const float4*>(W + (size_t)r * GIN);
    const float4* gv = reinterpret_cast<const float4*>(gi + i * GIN);
    float acc = 0.f;
    for (int k = lane; k < GIN / 4; k += 64) {
        float4 w4 = Wr[k];
        float4 g4 = gv[k];
        acc += w4.x * g4.x + w4.y * g4.y + w4.z * g4.z + w4.w * g4.w;
    }
    #pragma unroll
    for (int off = 32; off; off >>= 1) acc += __shfl_down(acc, off, 64);
    if (lane == 0) xbuf[i * (2 * GOUT) + rr] = acc + gb[r];   // parity 0
}

// 256-thread LN stats over a 768-float shared buffer
__device__ __forceinline__ void ln_stats_768(const float* __restrict__ buf,
                                             float* __restrict__ red,
                                             int tid, float& mu, float& rs)
{
    float s1 = 0.f, s2 = 0.f;
    for (int idx = tid; idx < 768; idx += 256) { float z = buf[idx]; s1 += z; s2 += z * z; }
    #pragma unroll
    for (int off = 32; off; off >>= 1) { s1 += __shfl_down(s1, off, 64); s2 += __shfl_down(s2, off, 64); }
    if ((tid & 63) == 0) { red[(tid >> 6) * 2] = s1; red[(tid >> 6) * 2 + 1] = s2; }
    __syncthreads();
    if (tid == 0) {
        float t1 = red[0] + red[2] + red[4] + red[6];
        float t2 = red[1] + red[3] + red[5] + red[7];
        float m = t1 * (1.f / 768.f);
        float v = t2 * (1.f / 768.f) - m * m;
        red[16] = m;
        red[17] = rsqrtf(v + EPS);
    }
    __syncthreads();
    mu = red[16]; rs = red[17];
}

// ---------------- cooperative mega-kernel: all 24 stages + pack ----------------
// Grid: 192 blocks x 256 threads. Per stage:
//   Phase A: block=(s,h)  attn partial -> xpart[s][h][768]
//   Phase B: block=(s,ug) head-reduce + residual + LNf + 8 cols of gelu(W2) -> gbuf; ug==0 stashes x
//   Phase C: block=(s,jg) W3 + residual -> ping-pong out (x[m2] transposed writeback)
__global__ __launch_bounds__(256) void k_mega(
    const float* __restrict__ lnxg, const float* __restrict__ lnxb,
    const float* __restrict__ lnyg, const float* __restrict__ lnyb,
    const float* __restrict__ wqw, const float* __restrict__ wqb,
    const float* __restrict__ wkw, const float* __restrict__ wkb,
    const float* __restrict__ wvw, const float* __restrict__ wvb,
    const float* __restrict__ l1w, const float* __restrict__ l1b,
    const float* __restrict__ lnfg, const float* __restrict__ lnfb,
    const float* __restrict__ l2w, const float* __restrict__ l2b,
    const float* __restrict__ l3w, const float* __restrict__ l3b,
    float* __restrict__ xbuf, float* __restrict__ xpart,
    float* __restrict__ gbuf, float* __restrict__ xstash,
    float* __restrict__ outp)
{
    cg::grid_group grid = cg::this_grid();
    __shared__ float smem[5984];
    float* red = smem + 5960;     // 20 floats

    int bb = blockIdx.x;
    int tid = threadIdx.x;
    int s = bb >> 4;              // slice 0..11
    int h = bb & 15;              // head / u-chunk / j-pair role

    int par0 = 0, par1 = 0, par2 = 0;
    const int pm1[3] = {0, 2, 1}, pm2[3] = {1, 0, 2};

    for (int l = 0; l < 8; ++l)
    for (int pp = 0; pp < 3; ++pp) {
        int m1 = pm1[pp], m2 = pm2[pp];
        int pa = (m1 == 0) ? par0 : (m1 == 1) ? par1 : par2;
        int pb = (m2 == 0) ? par0 : (m2 == 1) ? par1 : par2;
        const float* in1 = xbuf + m1 * 9216 + pa * 4608;
        const float* in2 = xbuf + m2 * 9216 + pb * 4608;
        float* out1 = xbuf + m1 * 9216 + (1 - pa) * 4608;
        float* out2 = xbuf + m2 * 9216 + (1 - pb) * 4608;
        int ls = l * S + s;

        // ================= Phase A =================
        {
            float* a  = smem;          // 768
            float* xn = smem + 768;
            float* yn = smem + 1536;
            float* q  = smem + 2304;
            float* kk = smem + 3072;
            float* vv = smem + 3840;
            float* oo = smem + 4608;   // ..5376
            float* sc = smem + 5376;   // 576 ..5952

            for (int idx = tid; idx < 768; idx += 256) {
                int r = idx >> 5, c = idx & 31;
                a[idx] = (r < S) ? in1[s * 384 + r * 32 + c]
                                 : in2[(r - S) * 384 + s * 32 + c];
            }
            __syncthreads();
            float mu, rs;
            ln_stats_768(a, red, tid, mu, rs);

            const float* gx = lnxg + ls * 768; const float* bx = lnxb + ls * 768;
            const float* gy = lnyg + ls * 768; const float* by = lnyb + ls * 768;
            for (int idx = tid; idx < 768; idx += 256) {
                float zn = (a[idx] - mu) * rs;
                xn[idx] = zn * gx[idx] + bx[idx];
                yn[idx] = zn * gy[idx] + by[idx];
            }
            __syncthreads();

            const float4* wq4 = (const float4*)(wqw + (size_t)ls * 16384 + h * 1024);
            const float4* wk4 = (const float4*)(wkw + (size_t)ls * 16384 + h * 1024);
            const float4* wv4 = (const float4*)(wvw + (size_t)ls * 16384 + h * 1024);
            const float* qb = wqb + ls * 512 + h * 32;
            const float* kb = wkb + ls * 512 + h * 32;
            const float* vb = wvb + ls * 512 + h * 32;
            for (int idx = tid; idx < 768; idx += 256) {
                int r = idx >> 5, j = idx & 31;
                const float4* xr = (const float4*)(xn + r * 32);
                const float4* yr = (const float4*)(yn + r * 32);
                float aq = qb[j], ak = kb[j], av = vb[j];
                #pragma unroll
                for (int c4 = 0; c4 < 8; c4++) {
                    float4 xv = xr[c4], yv = yr[c4];
                    aq += dot4(xv, wq4[j * 8 + c4]);
                    ak += dot4(yv, wk4[j * 8 + c4]);
                    av += dot4(yv, wv4[j * 8 + c4]);
                }
                q[idx] = aq; kk[idx] = ak; vv[idx] = av;
            }
            __syncthreads();

            for (int idx = tid; idx < 576; idx += 256) {
                int r = idx / 24, j = idx - r * 24;
                const float4* qr = (const float4*)(q + r * 32);
                const float4* kr = (const float4*)(kk + j * 32);
                float acc = 0.f;
                #pragma unroll
                for (int c4 = 0; c4 < 8; c4++) acc += dot4(qr[c4], kr[c4]);
                sc[idx] = acc * 0.17677669529663687f;
            }
            __syncthreads();

            for (int idx = tid; idx < 768; idx += 256) {
                int r = idx >> 5, c = idx & 31;
                const float* sr = sc + r * 24;
                float acc = 0.f;
                #pragma unroll
                for (int j = 0; j < 24; j++) acc += sr[j] * vv[j * 32 + c];
                oo[idx] = acc;
            }
            __syncthreads();

            const float4* w14 = (const float4*)(l1w + (size_t)ls * 16384 + h * 32);
            float* xp = xpart + (s * 16 + h) * 768;
            for (int idx = tid; idx < 768; idx += 256) {
                int r = idx >> 5, j = idx & 31;
                const float4* orow = (const float4*)(oo + r * 32);
                float acc = 0.f;
                #pragma unroll
                for (int c4 = 0; c4 < 8; c4++) acc += dot4(orow[c4], w14[j * 128 + c4]);
                xp[idx] = acc;
            }
        }
        grid.sync();

        // ================= Phase B =================
        {
            float* x  = smem;          // 768
            float* hn = smem + 768;    // 768
            const float* b1 = l1b + ls * 32;
            for (int idx = tid; idx < 768; idx += 256) {
                int r = idx >> 5, c = idx & 31;
                float av = (r < S) ? in1[s * 384 + r * 32 + c]
                                   : in2[(r - S) * 384 + s * 32 + c];
                float acc = av + b1[c];
                const float* xp = xpart + s * 16 * 768 + idx;
                #pragma unroll
                for (int hh = 0; hh < 16; hh++) acc += xp[hh * 768];
                x[idx] = acc;
            }
            __syncthreads();
            float mu2, rs2;
            ln_stats_768(x, red, tid, mu2, rs2);

            const float* gf = lnfg + ls * 768; const float* bf = lnfb + ls * 768;
            for (int idx = tid; idx < 768; idx += 256)
                hn[idx] = (x[idx] - mu2) * rs2 * gf[idx] + bf[idx];
            if (h == 0)
                for (int idx = tid; idx < 768; idx += 256)
                    xstash[s * 768 + idx] = x[idx];
            __syncthreads();

            if (tid < 192) {
                int r = tid >> 3, uu = tid & 7;
                int u = h * 8 + uu;
                const float4* hr = (const float4*)(hn + r * 32);
                const float4* w24 = (const float4*)(l2w + (size_t)ls * 4096);
                float acc = l2b[ls * 128 + u];
                #pragma unroll
                for (int c4 = 0; c4 < 8; c4++) acc += dot4(hr[c4], w24[u * 8 + c4]);
                gbuf[s * 3072 + r * 128 + u] = acc * 0.5f * (1.f + erff(acc * 0.70710678118654752f));
            }
        }
        grid.sync();

        // ================= Phase C =================
        {
            if (tid < 192) {
                int oidx = tid >> 2, uq = tid & 3;      // 48 outputs x 4-way u-split
                int r = oidx >> 1, j = h * 2 + (oidx & 1);
                const float4* gr  = (const float4*)(gbuf + s * 3072 + r * 128);
                const float4* w34 = (const float4*)(l3w + (size_t)ls * 4096 + j * 128);
                float p = 0.f;
                #pragma unroll
                for (int u4 = uq * 8; u4 < uq * 8 + 8; u4++) p += dot4(gr[u4], w34[u4]);
                p += __shfl_down(p, 2, 4);
                p += __shfl_down(p, 1, 4);
                if (uq == 0) {
                    float v = xstash[s * 768 + r * 32 + j] + l3b[ls * 32 + j] + p;
                    if (r < S) out1[s * 384 + r * 32 + j] = v;
                    else       out2[s * 384 + (r - S) * 32 + j] = v;
                }
            }
        }
        if (m1 == 0) par0 ^= 1; else if (m1 == 1) par1 ^= 1; else par2 ^= 1;
        if (m2 == 0) par0 ^= 1; else if (m2 == 1) par1 ^= 1; else par2 ^= 1;
        grid.sync();
    }

    // ---- pack: out[((a*3+i)*12+b)*32+c] = x_i[a][b][c] (final parity = 0,0,0) ----
    for (int idx = bb * 256 + tid; idx < 3 * 144 * 32; idx += 192 * 256) {
        int c = idx & 31;
        int r = idx >> 5;
        int b = r % 12;
        int ai = r / 12;
        int i = ai % 3;
        int a = ai / 3;
        int pi = (i == 0) ? par0 : (i == 1) ? par1 : par2;
        const float* xs = xbuf + i * 9216 + pi * 4608;
        outp[idx] = xs[a * 384 + b * 32 + c];
    }
}

extern "C" void kernel_launch(void* const* d_in, const int* in_sizes, int n_in,
                              void* d_out, int out_size, void* d_ws, size_t ws_size,
                              hipStream_t stream) {
    const float* input_t = (const float*)d_in[0];
    const float* input_s = (const float*)d_in[1];
    const float* s2g_w   = (const float*)d_in[2];
    const float* s2g_b   = (const float*)d_in[3];
    const float* g2g_w   = (const float*)d_in[4];
    const float* g2g_b   = (const float*)d_in[5];
    const float* lnx_g   = (const float*)d_in[6];
    const float* lnx_b   = (const float*)d_in[7];
    const float* lny_g   = (const float*)d_in[8];
    const float* lny_b   = (const float*)d_in[9];
    const float* lnf_g   = (const float*)d_in[10];
    const float* lnf_b   = (const float*)d_in[11];
    const float* wq_w    = (const float*)d_in[12];
    const float* wq_b    = (const float*)d_in[13];
    const float* wk_w    = (const float*)d_in[14];
    const float* wk_b    = (const float*)d_in[15];
    const float* wv_w    = (const float*)d_in[16];
    const float* wv_b    = (const float*)d_in[17];
    const float* l1_w    = (const float*)d_in[18];
    const float* l1_b    = (const float*)d_in[19];
    const float* l2_w    = (const float*)d_in[20];
    const float* l2_b    = (const float*)d_in[21];
    const float* l3_w    = (const float*)d_in[22];
    const float* l3_b    = (const float*)d_in[23];

    float* ws = (float*)d_ws;
    float* gi     = ws;                     // 36720
    float* xbuf   = ws + 36720;             // 27648
    float* xpart  = ws + 64368;             // 147456
    float* gbuf   = ws + 211824;            // 36864
    float* xstash = ws + 248688;            // 9216
    float* outp   = (float*)d_out;

    k_prep<<<144, 256, 0, stream>>>(input_t, input_s, s2g_w, s2g_b, gi);
    k_g2g<<<3456, 256, 0, stream>>>(g2g_w, g2g_b, gi, xbuf);

    void* args[] = {
        (void*)&lnx_g, (void*)&lnx_b, (void*)&lny_g, (void*)&lny_b,
        (void*)&wq_w, (void*)&wq_b, (void*)&wk_w, (void*)&wk_b,
        (void*)&wv_w, (void*)&wv_b, (void*)&l1_w, (void*)&l1_b,
        (void*)&lnf_g, (void*)&lnf_b, (void*)&l2_w, (void*)&l2_b,
        (void*)&l3_w, (void*)&l3_b,
        (void*)&xbuf, (void*)&xpart, (void*)&gbuf, (void*)&xstash,
        (void*)&outp
    };
    hipLaunchCooperativeKernel((const void*)k_mega, dim3(192), dim3(256),
                               args, 0, stream);
}

// Round 5
// 1486.017 us; speedup vs baseline: 2.2360x; 1.4487x over previous
//
#include <hip/hip_runtime.h>
#include <hip/hip_bf16.h>
#include <math.h>

// Sizes
#define S 12
#define C 32
#define T 7
#define GIN 12240         // S*S*(T*S+1)
#define GOUT 4608         // S*S*C
#define EPS 1e-5f

__device__ __forceinline__ float dot4(float4 a, float4 b) {
    return a.x * b.x + a.y * b.y + a.z * b.z + a.w * b.w;
}

// ---------------- prep: build gi[3][12240] ----------------
__global__ __launch_bounds__(256) void k_prep(
    const float* __restrict__ it, const float* __restrict__ is_,
    const float* __restrict__ s2w, const float* __restrict__ s2b,
    float* __restrict__ gi)
{
    int idx = blockIdx.x * 256 + threadIdx.x;
    if (idx >= 3 * GIN) return;
    int i = idx / GIN, rem = idx % GIN;
    int ab = rem / 85, e = rem % 85;
    int a = ab / S, b = ab % S;
    float val;
    if (e < 84) {
        int k = e / T, t = e % T;
        int x, y, z;
        if (i == 0)      { x = a; y = b; z = k; }
        else if (i == 1) { x = b; y = k; z = a; }
        else             { x = k; y = a; z = b; }
        val = it[((t * S + x) * S + y) * S + z];
    } else {
        float acc = s2b[i * 144 + ab];
        const float* wr = s2w + (i * 144 + ab) * 8;
        #pragma unroll
        for (int u = 0; u < 8; u++) acc += wr[u] * is_[u];
        val = acc;
    }
    gi[idx] = val;
}

// ---------------- g2g: x[i] = W[i] @ gi[i] + b[i], one wave per row ----------------
__global__ __launch_bounds__(256) void k_g2g(
    const float* __restrict__ W, const float* __restrict__ gb,
    const float* __restrict__ gi, float* __restrict__ xbuf)
{
    int wave = threadIdx.x >> 6;
    int lane = threadIdx.x & 63;
    int r = blockIdx.x * 4 + wave;          // 0..13823
    int i = r / GOUT, rr = r % GOUT;
    const float4* Wr = reinterpret_cast<const float4*>(W + (size_t)r * GIN);
    const float4* gv = reinterpret_cast<const float4*>(gi + i * GIN);
    float acc = 0.f;
    for (int k = lane; k < GIN / 4; k += 64) {
        float4 w4 = Wr[k];
        float4 g4 = gv[k];
        acc += w4.x * g4.x + w4.y * g4.y + w4.z * g4.z + w4.w * g4.w;
    }
    #pragma unroll
    for (int off = 32; off; off >>= 1) acc += __shfl_down(acc, off, 64);
    if (lane == 0) xbuf[i * (2 * GOUT) + rr] = acc + gb[r];   // parity 0
}

// ---------------- K1: per (slice, head): LN + QKV + scores + O + W1 partial ----------------
// 512 threads (8 waves) for latency hiding; weights read from global (L1/L2-cached).
__global__ __launch_bounds__(512) void k_attn(
    const float* __restrict__ xm1, const float* __restrict__ xm2,
    const float* __restrict__ lnxg, const float* __restrict__ lnxb,
    const float* __restrict__ lnyg, const float* __restrict__ lnyb,
    const float* __restrict__ wqw, const float* __restrict__ wqb,
    const float* __restrict__ wkw, const float* __restrict__ wkb,
    const float* __restrict__ wvw, const float* __restrict__ wvb,
    const float* __restrict__ l1w,
    float* __restrict__ xpart, int l)
{
    int s = blockIdx.x >> 4, h = blockIdx.x & 15;
    int tid = threadIdx.x;
    int ls = l * S + s;
    __shared__ float a[768], xn[768], yn[768], q[768], kk[768], vv[768], oo[768];
    __shared__ float sc[576];
    __shared__ float red[36];

    // ---- register prefetch (issued before any barrier; latency hides under a-load+LN) ----
    const float* gx = lnxg + ls * 768; const float* bx = lnxb + ls * 768;
    const float* gy = lnyg + ls * 768; const float* by = lnyb + ls * 768;
    float gx0 = gx[tid], bx0 = bx[tid], gy0 = gy[tid], by0 = by[tid];
    float gx1 = 0.f, bx1 = 0.f, gy1 = 0.f, by1 = 0.f;
    if (tid < 256) { gx1 = gx[tid + 512]; bx1 = bx[tid + 512]; gy1 = gy[tid + 512]; by1 = by[tid + 512]; }
    int jj = tid & 31;   // same j for both loop iterations (512 % 32 == 0)
    float qbv = wqb[ls * 512 + h * 32 + jj];
    float kbv = wkb[ls * 512 + h * 32 + jj];
    float vbv = wvb[ls * 512 + h * 32 + jj];

    // ---- load a = [x[m1][s] ; x[m2][:,s]] ----
    for (int idx = tid; idx < 768; idx += 512) {
        int r = idx >> 5, c = idx & 31;
        a[idx] = (r < S) ? xm1[s * 384 + r * 32 + c]
                         : xm2[(r - S) * 384 + s * 32 + c];
    }
    __syncthreads();

    // ---- full-matrix LN stats (8 waves) ----
    {
        float s1 = 0.f, s2 = 0.f;
        for (int idx = tid; idx < 768; idx += 512) { float z = a[idx]; s1 += z; s2 += z * z; }
        #pragma unroll
        for (int off = 32; off; off >>= 1) { s1 += __shfl_down(s1, off, 64); s2 += __shfl_down(s2, off, 64); }
        if ((tid & 63) == 0) { red[(tid >> 6) * 2] = s1; red[(tid >> 6) * 2 + 1] = s2; }
        __syncthreads();
        if (tid == 0) {
            float t1 = 0.f, t2 = 0.f;
            #pragma unroll
            for (int w = 0; w < 8; w++) { t1 += red[w * 2]; t2 += red[w * 2 + 1]; }
            float m = t1 * (1.f / 768.f);
            float v = t2 * (1.f / 768.f) - m * m;
            red[32] = m;
            red[33] = rsqrtf(v + EPS);
        }
        __syncthreads();
    }
    float mu = red[32], rs = red[33];

    // ---- LN apply from prefetched regs ----
    {
        float zn = (a[tid] - mu) * rs;
        xn[tid] = zn * gx0 + bx0;
        yn[tid] = zn * gy0 + by0;
    }
    if (tid < 256) {
        int idx = tid + 512;
        float zn = (a[idx] - mu) * rs;
        xn[idx] = zn * gx1 + bx1;
        yn[idx] = zn * gy1 + by1;
    }
    __syncthreads();

    // ---- QKV for head h ----
    const float4* wq4 = (const float4*)(wqw + (size_t)ls * 16384 + h * 1024);
    const float4* wk4 = (const float4*)(wkw + (size_t)ls * 16384 + h * 1024);
    const float4* wv4 = (const float4*)(wvw + (size_t)ls * 16384 + h * 1024);
    for (int idx = tid; idx < 768; idx += 512) {
        int r = idx >> 5, j = idx & 31;
        const float4* xr = (const float4*)(xn + r * 32);
        const float4* yr = (const float4*)(yn + r * 32);
        float aq = qbv, ak = kbv, av = vbv;
        #pragma unroll
        for (int c4 = 0; c4 < 8; c4++) {
            float4 xv = xr[c4], yv = yr[c4];
            aq += dot4(xv, wq4[j * 8 + c4]);
            ak += dot4(yv, wk4[j * 8 + c4]);
            av += dot4(yv, wv4[j * 8 + c4]);
        }
        q[idx] = aq; kk[idx] = ak; vv[idx] = av;
    }
    __syncthreads();

    // ---- scores 24x24 (no softmax) ----
    for (int idx = tid; idx < 576; idx += 512) {
        int r = idx / 24, j = idx - r * 24;
        const float4* qr = (const float4*)(q + r * 32);
        const float4* kr = (const float4*)(kk + j * 32);
        float acc = 0.f;
        #pragma unroll
        for (int c4 = 0; c4 < 8; c4++) acc += dot4(qr[c4], kr[c4]);
        sc[idx] = acc * 0.17677669529663687f;   // 1/sqrt(32)
    }
    __syncthreads();

    // ---- o = sc @ v (24x32) ----
    for (int idx = tid; idx < 768; idx += 512) {
        int r = idx >> 5, c = idx & 31;
        const float* sr = sc + r * 24;
        float acc = 0.f;
        #pragma unroll
        for (int j = 0; j < 24; j++) acc += sr[j] * vv[j * 32 + c];
        oo[idx] = acc;
    }
    __syncthreads();

    // ---- xpart = o_h @ w1_h^T ----
    const float4* w14 = (const float4*)(l1w + (size_t)ls * 16384 + h * 32);
    float* xp = xpart + (s * 16 + h) * 768;
    for (int idx = tid; idx < 768; idx += 512) {
        int r = idx >> 5, j = idx & 31;
        const float4* orow = (const float4*)(oo + r * 32);
        float acc = 0.f;
        #pragma unroll
        for (int c4 = 0; c4 < 8; c4++) acc += dot4(orow[c4], w14[j * 128 + c4]);
        xp[idx] = acc;
    }
}

// ---------------- K2: reduce heads + residual + LN + FFN (12 blocks x 1024 threads) ----------------
__global__ __launch_bounds__(1024) void k_ffn(
    const float* __restrict__ xm1, const float* __restrict__ xm2,
    const float* __restrict__ xpart,
    const float* __restrict__ l1b,
    const float* __restrict__ lnfg, const float* __restrict__ lnfb,
    const float* __restrict__ l2w, const float* __restrict__ l2b,
    const float* __restrict__ l3w, const float* __restrict__ l3b,
    float* __restrict__ out_m1, float* __restrict__ out_m2, int l)
{
    int s = blockIdx.x;
    int tid = threadIdx.x;
    int ls = l * S + s;
    __shared__ float x[768], hn[768], g[3072];
    __shared__ float red[36];

    // prefetch LN params
    float gf0 = 0.f, bf0 = 0.f;
    if (tid < 768) { gf0 = lnfg[ls * 768 + tid]; bf0 = lnfb[ls * 768 + tid]; }

    // ---- x = a + b1 + sum of 16 head partials ----
    if (tid < 768) {
        int r = tid >> 5, c = tid & 31;
        float av = (r < S) ? xm1[s * 384 + r * 32 + c]
                           : xm2[(r - S) * 384 + s * 32 + c];
        float acc = av + l1b[ls * 32 + c];
        const float* xp = xpart + s * 16 * 768 + tid;
        #pragma unroll
        for (int hh = 0; hh < 16; hh++) acc += xp[hh * 768];
        x[tid] = acc;
    }
    __syncthreads();

    // ---- LN stats (16 waves; waves >= 12 contribute zeros) ----
    {
        float s1 = 0.f, s2 = 0.f;
        if (tid < 768) { float z = x[tid]; s1 = z; s2 = z * z; }
        #pragma unroll
        for (int off = 32; off; off >>= 1) { s1 += __shfl_down(s1, off, 64); s2 += __shfl_down(s2, off, 64); }
        if ((tid & 63) == 0) { red[(tid >> 6) * 2] = s1; red[(tid >> 6) * 2 + 1] = s2; }
        __syncthreads();
        if (tid == 0) {
            float t1 = 0.f, t2 = 0.f;
            #pragma unroll
            for (int w = 0; w < 16; w++) { t1 += red[w * 2]; t2 += red[w * 2 + 1]; }
            float m = t1 * (1.f / 768.f);
            float v = t2 * (1.f / 768.f) - m * m;
            red[32] = m;
            red[33] = rsqrtf(v + EPS);
        }
        __syncthreads();
    }
    float mu = red[32], rs = red[33];

    if (tid < 768) hn[tid] = (x[tid] - mu) * rs * gf0 + bf0;
    __syncthreads();

    // ---- g = gelu(hn @ w2^T + b2)  (24x128), exact gelu ----
    const float4* w24 = (const float4*)(l2w + (size_t)ls * 4096);
    for (int idx = tid; idx < 3072; idx += 1024) {
        int r = idx >> 7, u = idx & 127;
        const float4* hr = (const float4*)(hn + r * 32);
        float acc = l2b[ls * 128 + u];
        #pragma unroll
        for (int c4 = 0; c4 < 8; c4++) acc += dot4(hr[c4], w24[u * 8 + c4]);
        g[idx] = acc * 0.5f * (1.f + erff(acc * 0.70710678118654752f));
    }
    __syncthreads();

    // ---- out = x + g @ w3^T + b3 (row s of both buffers; x[m2] transposed writeback) ----
    const float4* w34 = (const float4*)(l3w + (size_t)ls * 4096);
    if (tid < 768) {
        int r = tid >> 5, j = tid & 31;
        const float4* gr = (const float4*)(g + r * 128);
        float acc = x[tid] + l3b[ls * 32 + j];
        #pragma unroll
        for (int u4 = 0; u4 < 32; u4++) acc += dot4(gr[u4], w34[j * 32 + u4]);
        if (r < S) out_m1[s * 384 + r * 32 + j] = acc;
        else       out_m2[s * 384 + (r - S) * 32 + j] = acc;
    }
}

// ---------------- pack: out[(a*3+i)*12+b][c] = x_i[a][b][c] ----------------
__global__ __launch_bounds__(256) void k_pack(
    const float* __restrict__ x0, const float* __restrict__ x1,
    const float* __restrict__ x2, float* __restrict__ out)
{
    int idx = blockIdx.x * 256 + threadIdx.x;
    if (idx >= 3 * 144 * 32) return;
    int c = idx & 31;
    int r = idx >> 5;
    int b = r % 12;
    int ai = r / 12;
    int i = ai % 3;
    int a = ai / 3;
    const float* xs = (i == 0) ? x0 : ((i == 1) ? x1 : x2);
    out[idx] = xs[a * 384 + b * 32 + c];
}

extern "C" void kernel_launch(void* const* d_in, const int* in_sizes, int n_in,
                              void* d_out, int out_size, void* d_ws, size_t ws_size,
                              hipStream_t stream) {
    const float* input_t = (const float*)d_in[0];
    const float* input_s = (const float*)d_in[1];
    const float* s2g_w   = (const float*)d_in[2];
    const float* s2g_b   = (const float*)d_in[3];
    const float* g2g_w   = (const float*)d_in[4];
    const float* g2g_b   = (const float*)d_in[5];
    const float* lnx_g   = (const float*)d_in[6];
    const float* lnx_b   = (const float*)d_in[7];
    const float* lny_g   = (const float*)d_in[8];
    const float* lny_b   = (const float*)d_in[9];
    const float* lnf_g   = (const float*)d_in[10];
    const float* lnf_b   = (const float*)d_in[11];
    const float* wq_w    = (const float*)d_in[12];
    const float* wq_b    = (const float*)d_in[13];
    const float* wk_w    = (const float*)d_in[14];
    const float* wk_b    = (const float*)d_in[15];
    const float* wv_w    = (const float*)d_in[16];
    const float* wv_b    = (const float*)d_in[17];
    const float* l1_w    = (const float*)d_in[18];
    const float* l1_b    = (const float*)d_in[19];
    const float* l2_w    = (const float*)d_in[20];
    const float* l2_b    = (const float*)d_in[21];
    const float* l3_w    = (const float*)d_in[22];
    const float* l3_b    = (const float*)d_in[23];

    float* ws = (float*)d_ws;
    float* gi    = ws;                       // 3*12240 = 36720
    float* xbuf  = ws + 36720;               // 3*2*4608 = 27648
    float* xpart = ws + 36720 + 27648;       // 12*16*768 = 147456

    k_prep<<<144, 256, 0, stream>>>(input_t, input_s, s2g_w, s2g_b, gi);
    k_g2g<<<3456, 256, 0, stream>>>(g2g_w, g2g_b, gi, xbuf);

    int par[3] = {0, 0, 0};
    const int pairs[3][2] = {{0, 1}, {2, 0}, {1, 2}};
    for (int l = 0; l < 8; l++) {
        for (int pp = 0; pp < 3; pp++) {
            int m1 = pairs[pp][0], m2 = pairs[pp][1];
            float* in1  = xbuf + m1 * 9216 + par[m1] * 4608;
            float* in2  = xbuf + m2 * 9216 + par[m2] * 4608;
            float* out1 = xbuf + m1 * 9216 + (1 - par[m1]) * 4608;
            float* out2 = xbuf + m2 * 9216 + (1 - par[m2]) * 4608;
            k_attn<<<192, 512, 0, stream>>>(in1, in2,
                lnx_g, lnx_b, lny_g, lny_b,
                wq_w, wq_b, wk_w, wk_b, wv_w, wv_b,
                l1_w, xpart, l);
            k_ffn<<<12, 1024, 0, stream>>>(in1, in2, xpart, l1_b,
                lnf_g, lnf_b, l2_w, l2_b, l3_w, l3_b,
                out1, out2, l);
            par[m1] ^= 1; par[m2] ^= 1;
        }
    }
    k_pack<<<54, 256, 0, stream>>>(
        xbuf + 0 * 9216 + par[0] * 4608,
        xbuf + 1 * 9216 + par[1] * 4608,
        xbuf + 2 * 9216 + par[2] * 4608,
        (float*)d_out);
}

// Round 6
// 653.685 us; speedup vs baseline: 5.0830x; 2.2733x over previous
//
#include <hip/hip_runtime.h>
#include <hip/hip_bf16.h>
#include <math.h>

// Sizes
#define S 12
#define C 32
#define T 7
#define GIN 12240         // S*S*(T*S+1)
#define GOUT 4608         // S*S*C
#define EPS 1e-5f

__device__ __forceinline__ float dot4(float4 a, float4 b) {
    return a.x * b.x + a.y * b.y + a.z * b.z + a.w * b.w;
}

// ---------------- prep: build gi[3][12240] ----------------
__global__ __launch_bounds__(256) void k_prep(
    const float* __restrict__ it, const float* __restrict__ is_,
    const float* __restrict__ s2w, const float* __restrict__ s2b,
    float* __restrict__ gi)
{
    int idx = blockIdx.x * 256 + threadIdx.x;
    if (idx >= 3 * GIN) return;
    int i = idx / GIN, rem = idx % GIN;
    int ab = rem / 85, e = rem % 85;
    int a = ab / S, b = ab % S;
    float val;
    if (e < 84) {
        int k = e / T, t = e % T;
        int x, y, z;
        if (i == 0)      { x = a; y = b; z = k; }
        else if (i == 1) { x = b; y = k; z = a; }
        else             { x = k; y = a; z = b; }
        val = it[((t * S + x) * S + y) * S + z];
    } else {
        float acc = s2b[i * 144 + ab];
        const float* wr = s2w + (i * 144 + ab) * 8;
        #pragma unroll
        for (int u = 0; u < 8; u++) acc += wr[u] * is_[u];
        val = acc;
    }
    gi[idx] = val;
}

// ---------------- g2g: x[i] = W[i] @ gi[i] + b[i], one wave per row ----------------
__global__ __launch_bounds__(256) void k_g2g(
    const float* __restrict__ W, const float* __restrict__ gb,
    const float* __restrict__ gi, float* __restrict__ xbuf)
{
    int wave = threadIdx.x >> 6;
    int lane = threadIdx.x & 63;
    int r = blockIdx.x * 4 + wave;          // 0..13823
    int i = r / GOUT, rr = r % GOUT;
    const float4* Wr = reinterpret_cast<const float4*>(W + (size_t)r * GIN);
    const float4* gv = reinterpret_cast<const float4*>(gi + i * GIN);
    float acc = 0.f;
    for (int k = lane; k < GIN / 4; k += 64) {
        float4 w4 = Wr[k];
        float4 g4 = gv[k];
        acc += w4.x * g4.x + w4.y * g4.y + w4.z * g4.z + w4.w * g4.w;
    }
    #pragma unroll
    for (int off = 32; off; off >>= 1) acc += __shfl_down(acc, off, 64);
    if (lane == 0) xbuf[i * (2 * GOUT) + rr] = acc + gb[r];   // parity 0
}

// ---------------- K1: per (slice, head): LN + QKV + scores + O + W1 partial ----------------
// EXACT round-1 body (proven 792us base): 256 threads.
__global__ __launch_bounds__(256) void k_attn(
    const float* __restrict__ xm1, const float* __restrict__ xm2,
    const float* __restrict__ lnxg, const float* __restrict__ lnxb,
    const float* __restrict__ lnyg, const float* __restrict__ lnyb,
    const float* __restrict__ wqw, const float* __restrict__ wqb,
    const float* __restrict__ wkw, const float* __restrict__ wkb,
    const float* __restrict__ wvw, const float* __restrict__ wvb,
    const float* __restrict__ l1w,
    float* __restrict__ xpart, int l)
{
    int s = blockIdx.x >> 4, h = blockIdx.x & 15;
    int tid = threadIdx.x;
    __shared__ float a[768], xn[768], yn[768], q[768], kk[768], vv[768], oo[768];
    __shared__ float sc[576];
    __shared__ float red[16];

    for (int idx = tid; idx < 768; idx += 256) {
        int r = idx >> 5, c = idx & 31;
        a[idx] = (r < S) ? xm1[s * 384 + r * 32 + c]
                         : xm2[(r - S) * 384 + s * 32 + c];
    }
    __syncthreads();

    float s1 = 0.f, s2 = 0.f;
    for (int idx = tid; idx < 768; idx += 256) { float z = a[idx]; s1 += z; s2 += z * z; }
    #pragma unroll
    for (int off = 32; off; off >>= 1) { s1 += __shfl_down(s1, off, 64); s2 += __shfl_down(s2, off, 64); }
    int wv = tid >> 6;
    if ((tid & 63) == 0) { red[wv * 2] = s1; red[wv * 2 + 1] = s2; }
    __syncthreads();
    if (tid == 0) {
        float t1 = red[0] + red[2] + red[4] + red[6];
        float t2 = red[1] + red[3] + red[5] + red[7];
        float mu = t1 * (1.f / 768.f);
        float var = t2 * (1.f / 768.f) - mu * mu;
        red[8] = mu;
        red[9] = rsqrtf(var + EPS);
    }
    __syncthreads();
    float mu = red[8], rs = red[9];

    int ls = l * S + s;
    const float* gx = lnxg + ls * 768; const float* bx = lnxb + ls * 768;
    const float* gy = lnyg + ls * 768; const float* by = lnyb + ls * 768;
    for (int idx = tid; idx < 768; idx += 256) {
        float zn = (a[idx] - mu) * rs;
        xn[idx] = zn * gx[idx] + bx[idx];
        yn[idx] = zn * gy[idx] + by[idx];
    }
    __syncthreads();

    const float4* wq4 = (const float4*)(wqw + (size_t)ls * 16384 + h * 1024);
    const float4* wk4 = (const float4*)(wkw + (size_t)ls * 16384 + h * 1024);
    const float4* wv4 = (const float4*)(wvw + (size_t)ls * 16384 + h * 1024);
    const float* qb = wqb + ls * 512 + h * 32;
    const float* kb = wkb + ls * 512 + h * 32;
    const float* vb = wvb + ls * 512 + h * 32;
    for (int idx = tid; idx < 768; idx += 256) {
        int r = idx >> 5, j = idx & 31;
        const float4* xr = (const float4*)(xn + r * 32);
        const float4* yr = (const float4*)(yn + r * 32);
        float aq = qb[j], ak = kb[j], av = vb[j];
        #pragma unroll
        for (int c4 = 0; c4 < 8; c4++) {
            float4 xv = xr[c4], yv = yr[c4];
            aq += dot4(xv, wq4[j * 8 + c4]);
            ak += dot4(yv, wk4[j * 8 + c4]);
            av += dot4(yv, wv4[j * 8 + c4]);
        }
        q[idx] = aq; kk[idx] = ak; vv[idx] = av;
    }
    __syncthreads();

    for (int idx = tid; idx < 576; idx += 256) {
        int r = idx / 24, j = idx - r * 24;
        const float4* qr = (const float4*)(q + r * 32);
        const float4* kr = (const float4*)(kk + j * 32);
        float acc = 0.f;
        #pragma unroll
        for (int c4 = 0; c4 < 8; c4++) acc += dot4(qr[c4], kr[c4]);
        sc[idx] = acc * 0.17677669529663687f;   // 1/sqrt(32)
    }
    __syncthreads();

    for (int idx = tid; idx < 768; idx += 256) {
        int r = idx >> 5, c = idx & 31;
        const float* sr = sc + r * 24;
        float acc = 0.f;
        #pragma unroll
        for (int j = 0; j < 24; j++) acc += sr[j] * vv[j * 32 + c];
        oo[idx] = acc;
    }
    __syncthreads();

    const float4* w14 = (const float4*)(l1w + (size_t)ls * 16384 + h * 32);
    float* xp = xpart + (s * 16 + h) * 768;
    for (int idx = tid; idx < 768; idx += 256) {
        int r = idx >> 5, j = idx & 31;
        const float4* orow = (const float4*)(oo + r * 32);
        float acc = 0.f;
        #pragma unroll
        for (int c4 = 0; c4 < 8; c4++) acc += dot4(orow[c4], w14[j * 128 + c4]);
        xp[idx] = acc;
    }
}

// ---------------- K2 v2: r-split FFN, 144 blocks x 256 threads ----------------
// block = (s, rg): rg in [0,12) owns token rows {2rg, 2rg+1}. Redundantly
// computes x (head-reduce + residual; needed for full-matrix LN stats),
// then only its 2 rows of gelu(W2) and W3 + writeback.
__global__ __launch_bounds__(256) void k_ffn(
    const float* __restrict__ xm1, const float* __restrict__ xm2,
    const float* __restrict__ xpart,
    const float* __restrict__ l1b,
    const float* __restrict__ lnfg, const float* __restrict__ lnfb,
    const float* __restrict__ l2w, const float* __restrict__ l2b,
    const float* __restrict__ l3w, const float* __restrict__ l3b,
    float* __restrict__ out_m1, float* __restrict__ out_m2, int l)
{
    int s = blockIdx.x / 12, rg = blockIdx.x % 12;
    int r0 = rg * 2;
    int tid = threadIdx.x;
    int ls = l * S + s;
    __shared__ float x[768], hn2[64], g2[256];
    __shared__ float red[16];

    // ---- x = a + b1 + sum of 16 head partials (full, for LN stats) ----
    for (int idx = tid; idx < 768; idx += 256) {
        int r = idx >> 5, c = idx & 31;
        float av = (r < S) ? xm1[s * 384 + r * 32 + c]
                           : xm2[(r - S) * 384 + s * 32 + c];
        float acc = av + l1b[ls * 32 + c];
        const float* xp = xpart + s * 16 * 768 + idx;
        #pragma unroll
        for (int hh = 0; hh < 16; hh++) acc += xp[hh * 768];
        x[idx] = acc;
    }
    __syncthreads();

    // ---- LN stats over full x (4 waves) ----
    {
        float s1 = 0.f, s2 = 0.f;
        for (int idx = tid; idx < 768; idx += 256) { float z = x[idx]; s1 += z; s2 += z * z; }
        #pragma unroll
        for (int off = 32; off; off >>= 1) { s1 += __shfl_down(s1, off, 64); s2 += __shfl_down(s2, off, 64); }
        if ((tid & 63) == 0) { red[(tid >> 6) * 2] = s1; red[(tid >> 6) * 2 + 1] = s2; }
        __syncthreads();
        if (tid == 0) {
            float t1 = red[0] + red[2] + red[4] + red[6];
            float t2 = red[1] + red[3] + red[5] + red[7];
            float m = t1 * (1.f / 768.f);
            float v = t2 * (1.f / 768.f) - m * m;
            red[8] = m;
            red[9] = rsqrtf(v + EPS);
        }
        __syncthreads();
    }
    float mu = red[8], rs = red[9];

    // ---- LN apply for own 2 rows only ----
    if (tid < 64) {
        int r = r0 + (tid >> 5), c = tid & 31;
        int idx = r * 32 + c;
        hn2[tid] = (x[idx] - mu) * rs * lnfg[ls * 768 + idx] + lnfb[ls * 768 + idx];
    }
    __syncthreads();

    // ---- g2 = gelu(hn2 @ W2^T + b2): 2 rows x 128 = 256 dots, 1/thread ----
    {
        int rr = tid >> 7, u = tid & 127;
        const float4* hr = (const float4*)(hn2 + rr * 32);
        const float4* w2r = (const float4*)(l2w + (size_t)ls * 4096 + u * 32);
        float acc = l2b[ls * 128 + u];
        #pragma unroll
        for (int c4 = 0; c4 < 8; c4++) acc += dot4(hr[c4], w2r[c4]);
        g2[rr * 128 + u] = acc * 0.5f * (1.f + erff(acc * 0.70710678118654752f));
    }
    __syncthreads();

    // ---- out = x + g2 @ W3^T + b3 for own 2 rows (4-way u-split per output) ----
    {
        int oi = tid >> 2, q = tid & 3;     // 64 outputs x 4 lanes
        int rr = oi >> 5, j = oi & 31;
        int r = r0 + rr;
        const float4* gr  = (const float4*)(g2 + rr * 128);
        const float4* w3r = (const float4*)(l3w + (size_t)ls * 4096 + j * 128);
        float p = 0.f;
        #pragma unroll
        for (int u4 = q * 8; u4 < q * 8 + 8; u4++) p += dot4(gr[u4], w3r[u4]);
        p += __shfl_down(p, 2, 4);
        p += __shfl_down(p, 1, 4);
        if (q == 0) {
            float val = x[r * 32 + j] + l3b[ls * 32 + j] + p;
            if (r < S) out_m1[s * 384 + r * 32 + j] = val;
            else       out_m2[s * 384 + (r - S) * 32 + j] = val;
        }
    }
}

// ---------------- pack: out[(a*3+i)*12+b][c] = x_i[a][b][c] ----------------
__global__ __launch_bounds__(256) void k_pack(
    const float* __restrict__ x0, const float* __restrict__ x1,
    const float* __restrict__ x2, float* __restrict__ out)
{
    int idx = blockIdx.x * 256 + threadIdx.x;
    if (idx >= 3 * 144 * 32) return;
    int c = idx & 31;
    int r = idx >> 5;
    int b = r % 12;
    int ai = r / 12;
    int i = ai % 3;
    int a = ai / 3;
    const float* xs = (i == 0) ? x0 : ((i == 1) ? x1 : x2);
    out[idx] = xs[a * 384 + b * 32 + c];
}

extern "C" void kernel_launch(void* const* d_in, const int* in_sizes, int n_in,
                              void* d_out, int out_size, void* d_ws, size_t ws_size,
                              hipStream_t stream) {
    const float* input_t = (const float*)d_in[0];
    const float* input_s = (const float*)d_in[1];
    const float* s2g_w   = (const float*)d_in[2];
    const float* s2g_b   = (const float*)d_in[3];
    const float* g2g_w   = (const float*)d_in[4];
    const float* g2g_b   = (const float*)d_in[5];
    const float* lnx_g   = (const float*)d_in[6];
    const float* lnx_b   = (const float*)d_in[7];
    const float* lny_g   = (const float*)d_in[8];
    const float* lny_b   = (const float*)d_in[9];
    const float* lnf_g   = (const float*)d_in[10];
    const float* lnf_b   = (const float*)d_in[11];
    const float* wq_w    = (const float*)d_in[12];
    const float* wq_b    = (const float*)d_in[13];
    const float* wk_w    = (const float*)d_in[14];
    const float* wk_b    = (const float*)d_in[15];
    const float* wv_w    = (const float*)d_in[16];
    const float* wv_b    = (const float*)d_in[17];
    const float* l1_w    = (const float*)d_in[18];
    const float* l1_b    = (const float*)d_in[19];
    const float* l2_w    = (const float*)d_in[20];
    const float* l2_b    = (const float*)d_in[21];
    const float* l3_w    = (const float*)d_in[22];
    const float* l3_b    = (const float*)d_in[23];

    float* ws = (float*)d_ws;
    float* gi    = ws;                       // 3*12240 = 36720
    float* xbuf  = ws + 36720;               // 3*2*4608 = 27648
    float* xpart = ws + 36720 + 27648;       // 12*16*768 = 147456

    k_prep<<<144, 256, 0, stream>>>(input_t, input_s, s2g_w, s2g_b, gi);
    k_g2g<<<3456, 256, 0, stream>>>(g2g_w, g2g_b, gi, xbuf);

    int par[3] = {0, 0, 0};
    const int pairs[3][2] = {{0, 1}, {2, 0}, {1, 2}};
    for (int l = 0; l < 8; l++) {
        for (int pp = 0; pp < 3; pp++) {
            int m1 = pairs[pp][0], m2 = pairs[pp][1];
            float* in1  = xbuf + m1 * 9216 + par[m1] * 4608;
            float* in2  = xbuf + m2 * 9216 + par[m2] * 4608;
            float* out1 = xbuf + m1 * 9216 + (1 - par[m1]) * 4608;
            float* out2 = xbuf + m2 * 9216 + (1 - par[m2]) * 4608;
            k_attn<<<192, 256, 0, stream>>>(in1, in2,
                lnx_g, lnx_b, lny_g, lny_b,
                wq_w, wq_b, wk_w, wk_b, wv_w, wv_b,
                l1_w, xpart, l);
            k_ffn<<<144, 256, 0, stream>>>(in1, in2, xpart, l1_b,
                lnf_g, lnf_b, l2_w, l2_b, l3_w, l3_b,
                out1, out2, l);
            par[m1] ^= 1; par[m2] ^= 1;
        }
    }
    k_pack<<<54, 256, 0, stream>>>(
        xbuf + 0 * 9216 + par[0] * 4608,
        xbuf + 1 * 9216 + par[1] * 4608,
        xbuf + 2 * 9216 + par[2] * 4608,
        (float*)d_out);
}